// Round 2
// baseline (204.269 us; speedup 1.0000x reference)
//
#include <hip/hip_runtime.h>

#define B_      2
#define DIM_    256
#define N_      4096
#define HEADS_  8
#define DINNER_ 512

typedef _Float16 half_t;
typedef _Float16 half8  __attribute__((ext_vector_type(8)));
typedef _Float16 half4v __attribute__((ext_vector_type(4)));
typedef _Float16 half2v __attribute__((ext_vector_type(2)));
typedef float    floatx4 __attribute__((ext_vector_type(4)));

#define SCL_    1.4426950408889634f  // log2(e), baked into Q,K
#define SHIFT2_ 20.0f                // fixed softmax shift (log2 domain)

// K=32 granule (64kappa x 64mu): halfoff(kappa,mu) =
//   ((kappa>>5)*4 + (mu>>4))*512 + (((kappa>>3)&3)*16 + (mu&15))*8 + (kappa&7)
// V tiles use the K=16 granule: off16(j,dd) =
//   ((j>>4)*4 + (dd>>4))*256 + (((j>>2)&3)*16 + (dd&15))*4 + (j&3)
// perm: [b][slab 0..23][ntile 0..63][4096 halfs]; slab<8: Q, <16: K, else V.
// xTg:  [b][ntile 0..63][kslab 0..3][4096 halfs]  (fmap in granule layout)

// ---------------- prep: weights -> A-frag fp16; fmap -> xTg granule fp16 -----
__global__ __launch_bounds__(256) void prep_all(const float* __restrict__ fmap,
                                                const float* __restrict__ w_qkv,
                                                const float* __restrict__ w_out,
                                                half_t* __restrict__ wqF,
                                                half_t* __restrict__ woF,
                                                half_t* __restrict__ xTg) {
    const int t = threadIdx.x, bx = blockIdx.x;
    __shared__ float Tl[64 * 68];
    if (bx < 96) {                 // w_qkv: 96 m-tiles x 256 k
        half_t* dst = wqF + (size_t)bx * 4096;
#pragma unroll
        for (int j = 0; j < 2; ++j) {
            const int cch = j * 256 + t;
            const int o = cch >> 4, m15 = cch & 15;
            const float4 a  = *(const float4*)&w_qkv[(size_t)(bx * 16 + m15) * 256 + o * 8];
            const float4 bb = *(const float4*)&w_qkv[(size_t)(bx * 16 + m15) * 256 + o * 8 + 4];
            half8 hv;
            hv[0] = (half_t)a.x;  hv[1] = (half_t)a.y;  hv[2] = (half_t)a.z;  hv[3] = (half_t)a.w;
            hv[4] = (half_t)bb.x; hv[5] = (half_t)bb.y; hv[6] = (half_t)bb.z; hv[7] = (half_t)bb.w;
            *(half8*)(dst + o * 128 + m15 * 8) = hv;
        }
    } else if (bx < 112) {         // w_out: 16 m-tiles x 512 k
        const int mt = bx - 96;
        half_t* dst = woF + (size_t)mt * 8192;
#pragma unroll
        for (int j = 0; j < 4; ++j) {
            const int cch = j * 256 + t;
            const int o = cch >> 4, m15 = cch & 15;
            const float4 a  = *(const float4*)&w_out[(size_t)(mt * 16 + m15) * 512 + o * 8];
            const float4 bb = *(const float4*)&w_out[(size_t)(mt * 16 + m15) * 512 + o * 8 + 4];
            half8 hv;
            hv[0] = (half_t)a.x;  hv[1] = (half_t)a.y;  hv[2] = (half_t)a.z;  hv[3] = (half_t)a.w;
            hv[4] = (half_t)bb.x; hv[5] = (half_t)bb.y; hv[6] = (half_t)bb.z; hv[7] = (half_t)bb.w;
            *(half8*)(dst + o * 128 + m15 * 8) = hv;
        }
    } else {                       // fmap [k][n] fp32 -> xTg granule fp16
        const int idx = bx - 112;
        const int n0 = (idx & 63) * 64, k0 = ((idx >> 6) & 3) * 64, b = idx >> 8;
        {
            const int kk = t >> 2, nq = (t & 3) * 16;
#pragma unroll
            for (int q = 0; q < 4; ++q) {
                float4 v = *(const float4*)&fmap[((size_t)b * DIM_ + k0 + kk) * N_ + n0 + nq + 4 * q];
                *(float4*)&Tl[kk * 68 + nq + 4 * q] = v;
            }
        }
        __syncthreads();
        {
            const int n = t >> 2, ko = (t & 3) * 16;   // kappa_local = ko..ko+15
            half8 h0, h1;
#pragma unroll
            for (int j = 0; j < 8; ++j) h0[j] = (half_t)Tl[(ko + j) * 68 + n];
#pragma unroll
            for (int j = 0; j < 8; ++j) h1[j] = (half_t)Tl[(ko + 8 + j) * 68 + n];
            half_t* dst = xTg + (((size_t)b * 64 + (n0 >> 6)) * 4 + (k0 >> 6)) * 4096;
            const int o0 = ((ko >> 5) * 4 + (n >> 4)) * 512 + (((ko >> 3) & 3) * 16 + (n & 15)) * 8;
            const int k8 = ko + 8;
            const int o1 = ((k8 >> 5) * 4 + (n >> 4)) * 512 + (((k8 >> 3) & 3) * 16 + (n & 15)) * 8;
            *(half8*)(dst + o0) = h0;
            *(half8*)(dst + o1) = h1;
        }
    }
}

// ---------------- GEMM1: qkv projection + fused sq; coalesced LDS-bounce -----
__global__ __launch_bounds__(256) void mm_qkv_mf(const half_t* __restrict__ wqF,
                                                 const half_t* __restrict__ xTg,
                                                 half_t* __restrict__ perm,
                                                 float* __restrict__ sq) {
    const int nt64 = blockIdx.x, by = blockIdx.y, b = blockIdx.z;
    const int t = threadIdx.x, w = t >> 6, L = t & 63, c = L & 15, g = L >> 4;
    const int mt = by * 4 + w;

    const half_t* Ab = wqF + (size_t)mt * 4096;
    const half_t* Bb = xTg + (((size_t)b * 64 + nt64) * 4) * 4096;

    __shared__ __align__(16) char smraw[8192 + 4352];
    half_t* VtH = (half_t*)smraw;                 // 4096-half granule bounce
    float*  red = (float*)(smraw + 8192);         // sq reduction, stride 17

    const floatx4 fz = {0.f, 0.f, 0.f, 0.f};
    floatx4 acc[4];
#pragma unroll
    for (int ns = 0; ns < 4; ++ns) acc[ns] = fz;

#pragma unroll
    for (int kc = 0; kc < 8; ++kc) {
        const half8 af = *(const half8*)(Ab + (kc * 4 + g) * 128 + c * 8);
        const half_t* Bs = Bb + (kc >> 1) * 4096 + (kc & 1) * 2048;
#pragma unroll
        for (int ns = 0; ns < 4; ++ns) {
            const half8 bf = *(const half8*)(Bs + ns * 512 + L * 8);   // linear, coalesced
            acc[ns] = __builtin_amdgcn_mfma_f32_16x16x32_f16(af, bf, acc[ns], 0, 0, 0);
        }
    }

    half_t* dst = perm + (((size_t)(b * 24 + by) * 64 + nt64) << 12);
    if (by < 16) {
        // Q/K scaled by log2e: kappa = d = 16w+4g+i, mu = 16ns+c.
        float part[4];
#pragma unroll
        for (int ns = 0; ns < 4; ++ns) {
            half_t hv[4];
            float s = 0.f;
#pragma unroll
            for (int i = 0; i < 4; ++i) {
                hv[i] = (half_t)(acc[ns][i] * SCL_);
                const float f = (float)hv[i];
                s = fmaf(f, f, s);
            }
            part[ns] = s;
            const int off = ((w >> 1) * 4 + ns) * 512 + (((2 * w + (g >> 1)) & 3) * 16 + c) * 8 + 4 * (g & 1);
            half2v p0, p1;
            p0[0] = hv[0]; p0[1] = hv[1];
            p1[0] = hv[2]; p1[1] = hv[3];
            *(half2v*)(VtH + off)     = p0;
            *(half2v*)(VtH + off + 2) = p1;
        }
#pragma unroll
        for (int ns = 0; ns < 4; ++ns)
            red[(ns * 16 + (w * 4 + g)) * 17 + c] = part[ns];
        __syncthreads();
#pragma unroll
        for (int j = 0; j < 2; ++j)
            *(half8*)(dst + t * 16 + j * 8) = *(half8*)(VtH + t * 16 + j * 8);
        if (t < 64) {
            const int ns = t >> 4, cc = t & 15;
            float s = 0.f;
#pragma unroll
            for (int wg = 0; wg < 16; ++wg) s += red[(ns * 16 + wg) * 17 + cc];
            const int tens = by >> 3, hh = by & 7;
            sq[((size_t)(tens * 16 + b * 8 + hh)) * N_ + nt64 * 64 + ns * 16 + cc] = s;
        }
    } else {
        // V: j = 16ns+c (spatial), dd = 16w+4g+i -> K=16 granule via LDS bounce
#pragma unroll
        for (int ns = 0; ns < 4; ++ns)
#pragma unroll
            for (int i = 0; i < 4; ++i)
                VtH[(ns * 4 + w) * 256 + ((c >> 2) * 16 + 4 * g + i) * 4 + (c & 3)] = (half_t)acc[ns][i];
        __syncthreads();
#pragma unroll
        for (int j = 0; j < 2; ++j)
            *(half8*)(dst + t * 16 + j * 8) = *(half8*)(VtH + t * 16 + j * 8);
    }
}

// ---------------- fused distance-attention, split-K x4, no-drain pipeline ----
// grid.x = 64: qb = bx&15 (256 queries), kh = bx>>4 (K-quarters). 1024 blocks
// -> 4 blocks/CU (LDS 36 KB), 32 waves/CU. Single lgkm-only barrier per iter;
// K/V prefetch after the barrier overlaps compute. Fixed-shift softmax ->
// partials add with no rescale (combined inline in mm_out).
// Phase-desync: wave w starts its nt walk at (w&3) so MFMA bursts of some
// waves overlap trans/VALU bursts of others; s_setprio(1) around MFMA
// clusters lets MFMA-ready waves win issue arbitration (T5).
__global__ __launch_bounds__(512) void attn_mfma(const half_t* __restrict__ perm,
                                                 const float* __restrict__ sq,
                                                 half_t* __restrict__ oh,
                                                 float* __restrict__ lbuf) {
    const int bx = blockIdx.x;
    const int qb = bx & 15, kh = bx >> 4;
    const int h = blockIdx.y, b = blockIdx.z;
    const int bh = b * HEADS_ + h;

    const half_t* Qb = perm + ((size_t)(b * 24 + h) << 18);
    const half_t* Kb = perm + ((size_t)(b * 24 + 8 + h) << 18);
    const half_t* Vb = perm + ((size_t)(b * 24 + 16 + h) << 18);
    const float* q2a = sq + (size_t)bh * N_;
    const float* k2a = sq + (size_t)(16 + bh) * N_;

    __shared__ __align__(16) half_t Kl[2][4096];
    __shared__ __align__(16) half_t Vl[2][4096];
    __shared__ __align__(16) float  k2l[1024];

    const int t = threadIdx.x, w = t >> 6, L = t & 63, c = L & 15, g = L >> 4;
    const floatx4 fz = {0.f, 0.f, 0.f, 0.f};

    // stage this K-quarter's k2 (4 KB) once; visible after iter-0 barrier
    *(float2*)&k2l[t * 2] = *(const float2*)&k2a[kh * 1024 + t * 2];

    // persistent Q B-frags for 2 subtiles
    const int tl = w >> 1;
    const int p0 = (w & 1) * 2, p1 = p0 + 1;
    const half_t* Qt = Qb + ((size_t)(qb * 4 + tl) << 12);
    const half8 bq0a = *(const half8*)(Qt + (0 * 4 + p0) * 512 + L * 8);
    const half8 bq1a = *(const half8*)(Qt + (1 * 4 + p0) * 512 + L * 8);
    const half8 bq0b = *(const half8*)(Qt + (0 * 4 + p1) * 512 + L * 8);
    const half8 bq1b = *(const half8*)(Qt + (1 * 4 + p1) * 512 + L * 8);
    const float q2la = q2a[qb * 256 + 64 * tl + 16 * p0 + c];
    const float q2lb = q2a[qb * 256 + 64 * tl + 16 * p1 + c];

    half4v aone;   // ones row m=0 for l-MFMA
    {
        const half_t ov = (c == 0) ? (half_t)1.0f : (half_t)0.0f;
        aone[0] = ov; aone[1] = ov; aone[2] = ov; aone[3] = ov;
    }

    floatx4 Oa[4], Ob[4];
    floatx4 laca = fz, lacb = fz;
#pragma unroll
    for (int dt = 0; dt < 4; ++dt) { Oa[dt] = fz; Ob[dt] = fz; }

    const int kt0 = kh * 16;
    half8 rk = *(const half8*)(Kb + ((size_t)kt0 << 12) + t * 8);
    half8 rv = *(const half8*)(Vb + ((size_t)kt0 << 12) + t * 8);

    const int ntrot = w & 3;   // per-wave phase rotation

    for (int it = 0; it < 16; ++it) {
        const int buf = it & 1;
        *(half8*)(&Kl[buf][t * 8]) = rk;     // waits vmcnt for rk/rv data dep only
        *(half8*)(&Vl[buf][t * 8]) = rv;
        // LDS-only barrier: vmcnt (prefetch) stays outstanding across it.
        asm volatile("s_waitcnt lgkmcnt(0)\n\ts_barrier" ::: "memory");
        if (it < 15) {                        // prefetch overlaps compute below
            rk = *(const half8*)(Kb + ((size_t)(kt0 + it + 1) << 12) + t * 8);
            rv = *(const half8*)(Vb + ((size_t)(kt0 + it + 1) << 12) + t * 8);
        }

#pragma unroll
        for (int ntx = 0; ntx < 4; ++ntx) {
            const int nt = (ntx + ntrot) & 3;
            const half8 ak0 = *(const half8*)(&Kl[buf][(0 * 4 + nt) * 512 + L * 8]);
            const half8 ak1 = *(const half8*)(&Kl[buf][(1 * 4 + nt) * 512 + L * 8]);
            __builtin_amdgcn_s_setprio(1);
            floatx4 Sa = __builtin_amdgcn_mfma_f32_16x16x32_f16(ak0, bq0a, fz, 0, 0, 0);
            Sa = __builtin_amdgcn_mfma_f32_16x16x32_f16(ak1, bq1a, Sa, 0, 0, 0);
            floatx4 Sb = __builtin_amdgcn_mfma_f32_16x16x32_f16(ak0, bq0b, fz, 0, 0, 0);
            Sb = __builtin_amdgcn_mfma_f32_16x16x32_f16(ak1, bq1b, Sb, 0, 0, 0);
            __builtin_amdgcn_s_setprio(0);
            const float4 k2v = *(const float4*)&k2l[it * 64 + 16 * nt + 4 * g];

            float pa[4], pb[4];
            const float k2arr[4] = {k2v.x, k2v.y, k2v.z, k2v.w};
#pragma unroll
            for (int i = 0; i < 4; ++i) {
                // |d2| instead of max(d2,0): abs is a free src modifier on sqrt
                pa[i] = __builtin_amdgcn_exp2f(
                    __builtin_amdgcn_sqrtf(__builtin_fabsf(fmaf(Sa[i], -2.0f, q2la + k2arr[i]))) - SHIFT2_);
                pb[i] = __builtin_amdgcn_exp2f(
                    __builtin_amdgcn_sqrtf(__builtin_fabsf(fmaf(Sb[i], -2.0f, q2lb + k2arr[i]))) - SHIFT2_);
            }
            half4v bpa, bpb;
            {
                const half2v a0 = __builtin_bit_cast(half2v, __builtin_amdgcn_cvt_pkrtz(pa[0], pa[1]));
                const half2v a1 = __builtin_bit_cast(half2v, __builtin_amdgcn_cvt_pkrtz(pa[2], pa[3]));
                bpa[0] = a0[0]; bpa[1] = a0[1]; bpa[2] = a1[0]; bpa[3] = a1[1];
                const half2v b0 = __builtin_bit_cast(half2v, __builtin_amdgcn_cvt_pkrtz(pb[0], pb[1]));
                const half2v b1 = __builtin_bit_cast(half2v, __builtin_amdgcn_cvt_pkrtz(pb[2], pb[3]));
                bpb[0] = b0[0]; bpb[1] = b0[1]; bpb[2] = b1[0]; bpb[3] = b1[1];
            }

            __builtin_amdgcn_s_setprio(1);
            laca = __builtin_amdgcn_mfma_f32_16x16x16f16(aone, bpa, laca, 0, 0, 0);
            lacb = __builtin_amdgcn_mfma_f32_16x16x16f16(aone, bpb, lacb, 0, 0, 0);
#pragma unroll
            for (int dt = 0; dt < 4; ++dt) {
                const half4v av = *(const half4v*)(&Vl[buf][(nt * 4 + dt) * 256 + L * 4]);
                Oa[dt] = __builtin_amdgcn_mfma_f32_16x16x16f16(av, bpa, Oa[dt], 0, 0, 0);
                Ob[dt] = __builtin_amdgcn_mfma_f32_16x16x16f16(av, bpb, Ob[dt], 0, 0, 0);
            }
            __builtin_amdgcn_s_setprio(0);
        }
    }

    // write unnormalized O-quarters (fp16, K=32 granule: kappa=dd, mu=16*plane+c)
    const int ntile = qb * 4 + tl;
    half_t* dst = oh + (size_t)kh * 4194304 + (((size_t)bh * 64 + ntile) << 12);
#pragma unroll
    for (int dt = 0; dt < 4; ++dt) {
        const int obase = ((dt >> 1) * 4) * 512 + (((2 * dt + (g >> 1)) & 3) * 16 + c) * 8 + 4 * (g & 1);
        const half2v a0 = __builtin_bit_cast(half2v, __builtin_amdgcn_cvt_pkrtz(Oa[dt][0], Oa[dt][1]));
        const half2v a1 = __builtin_bit_cast(half2v, __builtin_amdgcn_cvt_pkrtz(Oa[dt][2], Oa[dt][3]));
        *(half2v*)(dst + obase + p0 * 512)     = a0;
        *(half2v*)(dst + obase + p0 * 512 + 2) = a1;
        const half2v b0 = __builtin_bit_cast(half2v, __builtin_amdgcn_cvt_pkrtz(Ob[dt][0], Ob[dt][1]));
        const half2v b1 = __builtin_bit_cast(half2v, __builtin_amdgcn_cvt_pkrtz(Ob[dt][2], Ob[dt][3]));
        *(half2v*)(dst + obase + p1 * 512)     = b0;
        *(half2v*)(dst + obase + p1 * 512 + 2) = b1;
    }
    // l: row m=0 of lac -> lanes 0..15, reg 0
    if (L < 16) {
        const size_t lb0 = (size_t)kh * 65536 + (size_t)bh * N_ + qb * 256 + 64 * tl;
        lbuf[lb0 + 16 * p0 + L] = laca[0];
        lbuf[lb0 + 16 * p1 + L] = lacb[0];
    }
}

// ---------------- GEMM3: out projection + split-K x4 combine inline ----------
// v2: the 4 waves of a block previously loaded the IDENTICAL B fragments and
// each redid the 4-quarter combine (~1 MB vmem issue per block per h). Now the
// combined tile (and combined 1/l) is staged in LDS once per block, double-
// buffered, with next-h quarter loads register-prefetched under the MFMAs.
__global__ __launch_bounds__(256) void mm_out_mf(const half_t* __restrict__ woF,
                                                 const half_t* __restrict__ oh,
                                                 const float* __restrict__ lbuf,
                                                 float* __restrict__ out) {
    const int nt64 = blockIdx.x, mb = blockIdx.y, b = blockIdx.z;
    const int t = threadIdx.x, w = t >> 6, L = t & 63, c = L & 15, g = L >> 4;
    const int mt = mb * 4 + w;

    const half_t* Ab = woF + (size_t)mt * 8192;
    const floatx4 fz = {0.f, 0.f, 0.f, 0.f};
    floatx4 O4[4];
#pragma unroll
    for (int ns = 0; ns < 4; ++ns) O4[ns] = fz;

    __shared__ __align__(16) half_t sh[2][4096];
    __shared__ float lsh[2][64];

    half8 r0[4], r1[4];
    float lr[4];

    auto LOADH = [&](int h) {
        const size_t toff = (((size_t)(b * 8 + h) * 64 + nt64) << 12) + t * 16;
#pragma unroll
        for (int q = 0; q < 4; ++q) {
            r0[q] = *(const half8*)(oh + (size_t)q * 4194304 + toff);
            r1[q] = *(const half8*)(oh + (size_t)q * 4194304 + toff + 8);
        }
        if (t < 64) {
            const size_t li = (size_t)(b * 8 + h) * N_ + nt64 * 64 + t;
#pragma unroll
            for (int q = 0; q < 4; ++q) lr[q] = lbuf[(size_t)q * 65536 + li];
        }
    };

    LOADH(0);
    for (int h = 0; h < 8; ++h) {
        const int buf = h & 1;
        // combine quarters (fixed-shift partials add) and stage once per block
        const half8 s0 = (r0[0] + r0[1]) + (r0[2] + r0[3]);
        const half8 s1 = (r1[0] + r1[1]) + (r1[2] + r1[3]);
        *(half8*)(&sh[buf][t * 16])     = s0;
        *(half8*)(&sh[buf][t * 16 + 8]) = s1;
        if (t < 64)
            lsh[buf][t] = __builtin_amdgcn_rcpf((lr[0] + lr[1]) + (lr[2] + lr[3]));
        __syncthreads();
        if (h < 7) LOADH(h + 1);          // prefetch next h under the MFMAs

        floatx4 acc[4];
#pragma unroll
        for (int ns = 0; ns < 4; ++ns) acc[ns] = fz;
#pragma unroll
        for (int c2 = 0; c2 < 2; ++c2) {
            const half8 af = *(const half8*)(Ab + (h * 8 + c2 * 4 + g) * 128 + c * 8);
#pragma unroll
            for (int ns = 0; ns < 4; ++ns) {
                const half8 bf = *(const half8*)(&sh[buf][(c2 * 4 + ns) * 512 + L * 8]);
                acc[ns] = __builtin_amdgcn_mfma_f32_16x16x32_f16(af, bf, acc[ns], 0, 0, 0);
            }
        }
#pragma unroll
        for (int ns = 0; ns < 4; ++ns) {
            const float inv = lsh[buf][ns * 16 + c];
#pragma unroll
            for (int i = 0; i < 4; ++i) O4[ns][i] = fmaf(acc[ns][i], inv, O4[ns][i]);
        }
    }

    float* Cg = out + ((size_t)b * DIM_ + mt * 16) * N_ + nt64 * 64;
#pragma unroll
    for (int ns = 0; ns < 4; ++ns)
#pragma unroll
        for (int i = 0; i < 4; ++i)
            Cg[(size_t)(4 * g + i) * N_ + ns * 16 + c] = O4[ns][i];
}

extern "C" void kernel_launch(void* const* d_in, const int* in_sizes, int n_in,
                              void* d_out, int out_size, void* d_ws, size_t ws_size,
                              hipStream_t stream) {
    const float* fmap  = (const float*)d_in[0];
    const float* w_qkv = (const float*)d_in[1];
    const float* w_out = (const float*)d_in[2];
    float* out = (float*)d_out;

    char* ws = (char*)d_ws;
    // Overlay plan: xTg and wqF are dead after mm_qkv; attn's oh overlays them.
    half_t* perm = (half_t*)ws;                       // 25,165,824 B
    float*  sq   = (float*) (ws + 25165824);          //    524,288 B
    float*  lbuf = (float*) (ws + 25690112);          // 4 x 262,144 B
    half_t* woF  = (half_t*)(ws + 26738688);          //    262,144 B (read by mm_out)
    half_t* oh   = (half_t*)(ws + 27000832);          // 4 x 8,388,608 B (after mm_qkv)
    half_t* xTg  = (half_t*)(ws + 27000832);          //  4,194,304 B (aliases oh)
    half_t* wqF  = (half_t*)(ws + 31195136);          //    786,432 B (aliases oh)

    prep_all <<<624, 256, 0, stream>>>(fmap, w_qkv, w_out, wqF, woF, xTg);
    mm_qkv_mf<<<dim3(64, 24, 2), 256, 0, stream>>>(wqF, xTg, perm, sq);
    attn_mfma<<<dim3(64, 8, 2), 512, 0, stream>>>(perm, sq, oh, lbuf);
    mm_out_mf<<<dim3(64, 4, 2), 256, 0, stream>>>(woF, oh, lbuf, out);
}

// Round 3
// 191.007 us; speedup vs baseline: 1.0694x; 1.0694x over previous
//
#include <hip/hip_runtime.h>

#define B_      2
#define DIM_    256
#define N_      4096
#define HEADS_  8
#define DINNER_ 512

typedef _Float16 half_t;
typedef _Float16 half8  __attribute__((ext_vector_type(8)));
typedef _Float16 half4v __attribute__((ext_vector_type(4)));
typedef _Float16 half2v __attribute__((ext_vector_type(2)));
typedef float    floatx4 __attribute__((ext_vector_type(4)));

#define SCL_    1.4426950408889634f  // log2(e), baked into Q,K
#define SHIFT2_ 20.0f                // fixed softmax shift (log2 domain)

// K=32 granule (64kappa x 64mu): halfoff(kappa,mu) =
//   ((kappa>>5)*4 + (mu>>4))*512 + (((kappa>>3)&3)*16 + (mu&15))*8 + (kappa&7)
// V tiles now ALSO use a K=32 granule, with the PV slot map chosen so the
// P B-frag is lane-local: slot k=g*8+j <-> logical key (j<4 ? lo16: g*4+j
//                                                       : hi16: g*4+j-4)
//   voff32(j,dd) = ((j>>5)*4 + (dd>>4))*512 + (((j>>2)&3)*16 + (dd&15))*8
//                  + ((j>>4)&1)*4 + (j&3)
// perm: [b][slab 0..23][ntile 0..63][4096 halfs]; slab<8: Q, <16: K, else V.
// xTg:  [b][ntile 0..63][kslab 0..3][4096 halfs]  (fmap in granule layout)

// ---------------- prep: weights -> A-frag fp16; fmap -> xTg granule fp16 -----
__global__ __launch_bounds__(256) void prep_all(const float* __restrict__ fmap,
                                                const float* __restrict__ w_qkv,
                                                const float* __restrict__ w_out,
                                                half_t* __restrict__ wqF,
                                                half_t* __restrict__ woF,
                                                half_t* __restrict__ xTg) {
    const int t = threadIdx.x, bx = blockIdx.x;
    __shared__ float Tl[64 * 68];
    if (bx < 96) {                 // w_qkv: 96 m-tiles x 256 k
        half_t* dst = wqF + (size_t)bx * 4096;
#pragma unroll
        for (int j = 0; j < 2; ++j) {
            const int cch = j * 256 + t;
            const int o = cch >> 4, m15 = cch & 15;
            const float4 a  = *(const float4*)&w_qkv[(size_t)(bx * 16 + m15) * 256 + o * 8];
            const float4 bb = *(const float4*)&w_qkv[(size_t)(bx * 16 + m15) * 256 + o * 8 + 4];
            half8 hv;
            hv[0] = (half_t)a.x;  hv[1] = (half_t)a.y;  hv[2] = (half_t)a.z;  hv[3] = (half_t)a.w;
            hv[4] = (half_t)bb.x; hv[5] = (half_t)bb.y; hv[6] = (half_t)bb.z; hv[7] = (half_t)bb.w;
            *(half8*)(dst + o * 128 + m15 * 8) = hv;
        }
    } else if (bx < 112) {         // w_out: 16 m-tiles x 512 k
        const int mt = bx - 96;
        half_t* dst = woF + (size_t)mt * 8192;
#pragma unroll
        for (int j = 0; j < 4; ++j) {
            const int cch = j * 256 + t;
            const int o = cch >> 4, m15 = cch & 15;
            const float4 a  = *(const float4*)&w_out[(size_t)(mt * 16 + m15) * 512 + o * 8];
            const float4 bb = *(const float4*)&w_out[(size_t)(mt * 16 + m15) * 512 + o * 8 + 4];
            half8 hv;
            hv[0] = (half_t)a.x;  hv[1] = (half_t)a.y;  hv[2] = (half_t)a.z;  hv[3] = (half_t)a.w;
            hv[4] = (half_t)bb.x; hv[5] = (half_t)bb.y; hv[6] = (half_t)bb.z; hv[7] = (half_t)bb.w;
            *(half8*)(dst + o * 128 + m15 * 8) = hv;
        }
    } else {                       // fmap [k][n] fp32 -> xTg granule fp16
        const int idx = bx - 112;
        const int n0 = (idx & 63) * 64, k0 = ((idx >> 6) & 3) * 64, b = idx >> 8;
        {
            const int kk = t >> 2, nq = (t & 3) * 16;
#pragma unroll
            for (int q = 0; q < 4; ++q) {
                float4 v = *(const float4*)&fmap[((size_t)b * DIM_ + k0 + kk) * N_ + n0 + nq + 4 * q];
                *(float4*)&Tl[kk * 68 + nq + 4 * q] = v;
            }
        }
        __syncthreads();
        {
            const int n = t >> 2, ko = (t & 3) * 16;   // kappa_local = ko..ko+15
            half8 h0, h1;
#pragma unroll
            for (int j = 0; j < 8; ++j) h0[j] = (half_t)Tl[(ko + j) * 68 + n];
#pragma unroll
            for (int j = 0; j < 8; ++j) h1[j] = (half_t)Tl[(ko + 8 + j) * 68 + n];
            half_t* dst = xTg + (((size_t)b * 64 + (n0 >> 6)) * 4 + (k0 >> 6)) * 4096;
            const int o0 = ((ko >> 5) * 4 + (n >> 4)) * 512 + (((ko >> 3) & 3) * 16 + (n & 15)) * 8;
            const int k8 = ko + 8;
            const int o1 = ((k8 >> 5) * 4 + (n >> 4)) * 512 + (((k8 >> 3) & 3) * 16 + (n & 15)) * 8;
            *(half8*)(dst + o0) = h0;
            *(half8*)(dst + o1) = h1;
        }
    }
}

// ---------------- GEMM1: qkv projection + fused sq; coalesced LDS-bounce -----
__global__ __launch_bounds__(256) void mm_qkv_mf(const half_t* __restrict__ wqF,
                                                 const half_t* __restrict__ xTg,
                                                 half_t* __restrict__ perm,
                                                 float* __restrict__ sq) {
    const int nt64 = blockIdx.x, by = blockIdx.y, b = blockIdx.z;
    const int t = threadIdx.x, w = t >> 6, L = t & 63, c = L & 15, g = L >> 4;
    const int mt = by * 4 + w;

    const half_t* Ab = wqF + (size_t)mt * 4096;
    const half_t* Bb = xTg + (((size_t)b * 64 + nt64) * 4) * 4096;

    __shared__ __align__(16) char smraw[8192 + 4352];
    half_t* VtH = (half_t*)smraw;                 // 4096-half granule bounce
    float*  red = (float*)(smraw + 8192);         // sq reduction, stride 17

    const floatx4 fz = {0.f, 0.f, 0.f, 0.f};
    floatx4 acc[4];
#pragma unroll
    for (int ns = 0; ns < 4; ++ns) acc[ns] = fz;

#pragma unroll
    for (int kc = 0; kc < 8; ++kc) {
        const half8 af = *(const half8*)(Ab + (kc * 4 + g) * 128 + c * 8);
        const half_t* Bs = Bb + (kc >> 1) * 4096 + (kc & 1) * 2048;
#pragma unroll
        for (int ns = 0; ns < 4; ++ns) {
            const half8 bf = *(const half8*)(Bs + ns * 512 + L * 8);   // linear, coalesced
            acc[ns] = __builtin_amdgcn_mfma_f32_16x16x32_f16(af, bf, acc[ns], 0, 0, 0);
        }
    }

    half_t* dst = perm + (((size_t)(b * 24 + by) * 64 + nt64) << 12);
    if (by < 16) {
        // Q/K scaled by log2e: kappa = d = 16w+4g+i, mu = 16ns+c.
        float part[4];
#pragma unroll
        for (int ns = 0; ns < 4; ++ns) {
            half_t hv[4];
            float s = 0.f;
#pragma unroll
            for (int i = 0; i < 4; ++i) {
                hv[i] = (half_t)(acc[ns][i] * SCL_);
                const float f = (float)hv[i];
                s = fmaf(f, f, s);
            }
            part[ns] = s;
            const int off = ((w >> 1) * 4 + ns) * 512 + (((2 * w + (g >> 1)) & 3) * 16 + c) * 8 + 4 * (g & 1);
            half2v p0, p1;
            p0[0] = hv[0]; p0[1] = hv[1];
            p1[0] = hv[2]; p1[1] = hv[3];
            *(half2v*)(VtH + off)     = p0;
            *(half2v*)(VtH + off + 2) = p1;
        }
#pragma unroll
        for (int ns = 0; ns < 4; ++ns)
            red[(ns * 16 + (w * 4 + g)) * 17 + c] = part[ns];
        __syncthreads();
#pragma unroll
        for (int j = 0; j < 2; ++j)
            *(half8*)(dst + t * 16 + j * 8) = *(half8*)(VtH + t * 16 + j * 8);
        if (t < 64) {
            const int ns = t >> 4, cc = t & 15;
            float s = 0.f;
#pragma unroll
            for (int wg = 0; wg < 16; ++wg) s += red[(ns * 16 + wg) * 17 + cc];
            const int tens = by >> 3, hh = by & 7;
            sq[((size_t)(tens * 16 + b * 8 + hh)) * N_ + nt64 * 64 + ns * 16 + cc] = s;
        }
    } else {
        // V: j = 16ns+c (spatial key), dd = 16w+4g+i -> K=32 PV granule:
        // voff32 = ((ns>>1)*4 + w)*512 + ((c>>2)*16 + 4g+i)*8 + (ns&1)*4 + (c&3)
#pragma unroll
        for (int ns = 0; ns < 4; ++ns)
#pragma unroll
            for (int i = 0; i < 4; ++i)
                VtH[((ns >> 1) * 4 + w) * 512 + ((c >> 2) * 16 + 4 * g + i) * 8 + (ns & 1) * 4 + (c & 3)] =
                    (half_t)acc[ns][i];
        __syncthreads();
#pragma unroll
        for (int j = 0; j < 2; ++j)
            *(half8*)(dst + t * 16 + j * 8) = *(half8*)(VtH + t * 16 + j * 8);
    }
}

// ---------------- fused distance-attention, split-K x4, no-drain pipeline ----
// grid.x = 64: qb = bx&15 (256 queries), kh = bx>>4 (K-quarters). 1024 blocks
// -> 4 blocks/CU (LDS 36 KB). Single lgkm-only barrier per iter; K/V prefetch
// after the barrier overlaps compute. Fixed-shift softmax -> partials add with
// no rescale (combined inline in mm_out).
// v3: PV and l-accum MFMAs converted from 16x16x16 (half-efficiency slot) to
// 16x16x32 by pairing key-subtiles; the P B-frag is lane-local because the
// V granule's K-slot map was co-designed with the QK output layout (see top).
__global__ __launch_bounds__(512) void attn_mfma(const half_t* __restrict__ perm,
                                                 const float* __restrict__ sq,
                                                 half_t* __restrict__ oh,
                                                 float* __restrict__ lbuf) {
    const int bx = blockIdx.x;
    const int qb = bx & 15, kh = bx >> 4;
    const int h = blockIdx.y, b = blockIdx.z;
    const int bh = b * HEADS_ + h;

    const half_t* Qb = perm + ((size_t)(b * 24 + h) << 18);
    const half_t* Kb = perm + ((size_t)(b * 24 + 8 + h) << 18);
    const half_t* Vb = perm + ((size_t)(b * 24 + 16 + h) << 18);
    const float* q2a = sq + (size_t)bh * N_;
    const float* k2a = sq + (size_t)(16 + bh) * N_;

    __shared__ __align__(16) half_t Kl[2][4096];
    __shared__ __align__(16) half_t Vl[2][4096];
    __shared__ __align__(16) float  k2l[1024];

    const int t = threadIdx.x, w = t >> 6, L = t & 63, c = L & 15, g = L >> 4;
    const floatx4 fz = {0.f, 0.f, 0.f, 0.f};

    // stage this K-quarter's k2 (4 KB) once; visible after iter-0 barrier
    *(float2*)&k2l[t * 2] = *(const float2*)&k2a[kh * 1024 + t * 2];

    // persistent Q B-frags for 2 subtiles
    const int tl = w >> 1;
    const int p0 = (w & 1) * 2, p1 = p0 + 1;
    const half_t* Qt = Qb + ((size_t)(qb * 4 + tl) << 12);
    const half8 bq0a = *(const half8*)(Qt + (0 * 4 + p0) * 512 + L * 8);
    const half8 bq1a = *(const half8*)(Qt + (1 * 4 + p0) * 512 + L * 8);
    const half8 bq0b = *(const half8*)(Qt + (0 * 4 + p1) * 512 + L * 8);
    const half8 bq1b = *(const half8*)(Qt + (1 * 4 + p1) * 512 + L * 8);
    const float q2la = q2a[qb * 256 + 64 * tl + 16 * p0 + c];
    const float q2lb = q2a[qb * 256 + 64 * tl + 16 * p1 + c];

    half8 aone8;   // ones row m=0 for K=32 l-MFMA
    {
        const half_t ov = (c == 0) ? (half_t)1.0f : (half_t)0.0f;
        aone8[0] = ov; aone8[1] = ov; aone8[2] = ov; aone8[3] = ov;
        aone8[4] = ov; aone8[5] = ov; aone8[6] = ov; aone8[7] = ov;
    }

    floatx4 Oa[4], Ob[4];
    floatx4 laca = fz, lacb = fz;
#pragma unroll
    for (int dt = 0; dt < 4; ++dt) { Oa[dt] = fz; Ob[dt] = fz; }

    const int kt0 = kh * 16;
    half8 rk = *(const half8*)(Kb + ((size_t)kt0 << 12) + t * 8);
    half8 rv = *(const half8*)(Vb + ((size_t)kt0 << 12) + t * 8);

    union H8 { half8 v; half2v h2[4]; };

    for (int it = 0; it < 16; ++it) {
        const int buf = it & 1;
        *(half8*)(&Kl[buf][t * 8]) = rk;     // waits vmcnt for rk/rv data dep only
        *(half8*)(&Vl[buf][t * 8]) = rv;
        // LDS-only barrier: vmcnt (prefetch) stays outstanding across it.
        asm volatile("s_waitcnt lgkmcnt(0)\n\ts_barrier" ::: "memory");
        if (it < 15) {                        // prefetch overlaps compute below
            rk = *(const half8*)(Kb + ((size_t)(kt0 + it + 1) << 12) + t * 8);
            rv = *(const half8*)(Vb + ((size_t)(kt0 + it + 1) << 12) + t * 8);
        }

#pragma unroll
        for (int ntp = 0; ntp < 2; ++ntp) {
            H8 ua, ub;   // K=32 P B-frags, filled lane-locally across the pair
#pragma unroll
            for (int hh = 0; hh < 2; ++hh) {
                const int nt = ntp * 2 + hh;
                const half8 ak0 = *(const half8*)(&Kl[buf][(0 * 4 + nt) * 512 + L * 8]);
                const half8 ak1 = *(const half8*)(&Kl[buf][(1 * 4 + nt) * 512 + L * 8]);
                floatx4 Sa = __builtin_amdgcn_mfma_f32_16x16x32_f16(ak0, bq0a, fz, 0, 0, 0);
                Sa = __builtin_amdgcn_mfma_f32_16x16x32_f16(ak1, bq1a, Sa, 0, 0, 0);
                floatx4 Sb = __builtin_amdgcn_mfma_f32_16x16x32_f16(ak0, bq0b, fz, 0, 0, 0);
                Sb = __builtin_amdgcn_mfma_f32_16x16x32_f16(ak1, bq1b, Sb, 0, 0, 0);
                const float4 k2v = *(const float4*)&k2l[it * 64 + 16 * nt + 4 * g];

                float pa[4], pb[4];
                const float k2arr[4] = {k2v.x, k2v.y, k2v.z, k2v.w};
#pragma unroll
                for (int i = 0; i < 4; ++i) {
                    // |d2| instead of max(d2,0): abs is a free src modifier on sqrt
                    pa[i] = __builtin_amdgcn_exp2f(
                        __builtin_amdgcn_sqrtf(__builtin_fabsf(fmaf(Sa[i], -2.0f, q2la + k2arr[i]))) - SHIFT2_);
                    pb[i] = __builtin_amdgcn_exp2f(
                        __builtin_amdgcn_sqrtf(__builtin_fabsf(fmaf(Sb[i], -2.0f, q2lb + k2arr[i]))) - SHIFT2_);
                }
                ua.h2[2 * hh]     = __builtin_bit_cast(half2v, __builtin_amdgcn_cvt_pkrtz(pa[0], pa[1]));
                ua.h2[2 * hh + 1] = __builtin_bit_cast(half2v, __builtin_amdgcn_cvt_pkrtz(pa[2], pa[3]));
                ub.h2[2 * hh]     = __builtin_bit_cast(half2v, __builtin_amdgcn_cvt_pkrtz(pb[0], pb[1]));
                ub.h2[2 * hh + 1] = __builtin_bit_cast(half2v, __builtin_amdgcn_cvt_pkrtz(pb[2], pb[3]));
            }

            laca = __builtin_amdgcn_mfma_f32_16x16x32_f16(aone8, ua.v, laca, 0, 0, 0);
            lacb = __builtin_amdgcn_mfma_f32_16x16x32_f16(aone8, ub.v, lacb, 0, 0, 0);
#pragma unroll
            for (int dt = 0; dt < 4; ++dt) {
                const half8 av = *(const half8*)(&Vl[buf][(ntp * 4 + dt) * 512 + L * 8]);
                Oa[dt] = __builtin_amdgcn_mfma_f32_16x16x32_f16(av, ua.v, Oa[dt], 0, 0, 0);
                Ob[dt] = __builtin_amdgcn_mfma_f32_16x16x32_f16(av, ub.v, Ob[dt], 0, 0, 0);
            }
        }
    }

    // write unnormalized O-quarters (fp16, K=32 granule: kappa=dd, mu=16*plane+c)
    const int ntile = qb * 4 + tl;
    half_t* dst = oh + (size_t)kh * 4194304 + (((size_t)bh * 64 + ntile) << 12);
#pragma unroll
    for (int dt = 0; dt < 4; ++dt) {
        const int obase = ((dt >> 1) * 4) * 512 + (((2 * dt + (g >> 1)) & 3) * 16 + c) * 8 + 4 * (g & 1);
        const half2v a0 = __builtin_bit_cast(half2v, __builtin_amdgcn_cvt_pkrtz(Oa[dt][0], Oa[dt][1]));
        const half2v a1 = __builtin_bit_cast(half2v, __builtin_amdgcn_cvt_pkrtz(Oa[dt][2], Oa[dt][3]));
        *(half2v*)(dst + obase + p0 * 512)     = a0;
        *(half2v*)(dst + obase + p0 * 512 + 2) = a1;
        const half2v b0 = __builtin_bit_cast(half2v, __builtin_amdgcn_cvt_pkrtz(Ob[dt][0], Ob[dt][1]));
        const half2v b1 = __builtin_bit_cast(half2v, __builtin_amdgcn_cvt_pkrtz(Ob[dt][2], Ob[dt][3]));
        *(half2v*)(dst + obase + p1 * 512)     = b0;
        *(half2v*)(dst + obase + p1 * 512 + 2) = b1;
    }
    // l: row m=0 of lac -> lanes 0..15, reg 0
    if (L < 16) {
        const size_t lb0 = (size_t)kh * 65536 + (size_t)bh * N_ + qb * 256 + 64 * tl;
        lbuf[lb0 + 16 * p0 + L] = laca[0];
        lbuf[lb0 + 16 * p1 + L] = lacb[0];
    }
}

// ---------------- GEMM3: out projection + split-K x4 combine inline ----------
// v2: combined quarter tile (and combined 1/l) staged in LDS once per block,
// double-buffered, next-h quarter loads register-prefetched under the MFMAs.
__global__ __launch_bounds__(256) void mm_out_mf(const half_t* __restrict__ woF,
                                                 const half_t* __restrict__ oh,
                                                 const float* __restrict__ lbuf,
                                                 float* __restrict__ out) {
    const int nt64 = blockIdx.x, mb = blockIdx.y, b = blockIdx.z;
    const int t = threadIdx.x, w = t >> 6, L = t & 63, c = L & 15, g = L >> 4;
    const int mt = mb * 4 + w;

    const half_t* Ab = woF + (size_t)mt * 8192;
    const floatx4 fz = {0.f, 0.f, 0.f, 0.f};
    floatx4 O4[4];
#pragma unroll
    for (int ns = 0; ns < 4; ++ns) O4[ns] = fz;

    __shared__ __align__(16) half_t sh[2][4096];
    __shared__ float lsh[2][64];

    half8 r0[4], r1[4];
    float lr[4];

    auto LOADH = [&](int h) {
        const size_t toff = (((size_t)(b * 8 + h) * 64 + nt64) << 12) + t * 16;
#pragma unroll
        for (int q = 0; q < 4; ++q) {
            r0[q] = *(const half8*)(oh + (size_t)q * 4194304 + toff);
            r1[q] = *(const half8*)(oh + (size_t)q * 4194304 + toff + 8);
        }
        if (t < 64) {
            const size_t li = (size_t)(b * 8 + h) * N_ + nt64 * 64 + t;
#pragma unroll
            for (int q = 0; q < 4; ++q) lr[q] = lbuf[(size_t)q * 65536 + li];
        }
    };

    LOADH(0);
    for (int h = 0; h < 8; ++h) {
        const int buf = h & 1;
        // combine quarters (fixed-shift partials add) and stage once per block
        const half8 s0 = (r0[0] + r0[1]) + (r0[2] + r0[3]);
        const half8 s1 = (r1[0] + r1[1]) + (r1[2] + r1[3]);
        *(half8*)(&sh[buf][t * 16])     = s0;
        *(half8*)(&sh[buf][t * 16 + 8]) = s1;
        if (t < 64)
            lsh[buf][t] = __builtin_amdgcn_rcpf((lr[0] + lr[1]) + (lr[2] + lr[3]));
        __syncthreads();
        if (h < 7) LOADH(h + 1);          // prefetch next h under the MFMAs

        floatx4 acc[4];
#pragma unroll
        for (int ns = 0; ns < 4; ++ns) acc[ns] = fz;
#pragma unroll
        for (int c2 = 0; c2 < 2; ++c2) {
            const half8 af = *(const half8*)(Ab + (h * 8 + c2 * 4 + g) * 128 + c * 8);
#pragma unroll
            for (int ns = 0; ns < 4; ++ns) {
                const half8 bf = *(const half8*)(&sh[buf][(c2 * 4 + ns) * 512 + L * 8]);
                acc[ns] = __builtin_amdgcn_mfma_f32_16x16x32_f16(af, bf, acc[ns], 0, 0, 0);
            }
        }
#pragma unroll
        for (int ns = 0; ns < 4; ++ns) {
            const float inv = lsh[buf][ns * 16 + c];
#pragma unroll
            for (int i = 0; i < 4; ++i) O4[ns][i] = fmaf(acc[ns][i], inv, O4[ns][i]);
        }
    }

    float* Cg = out + ((size_t)b * DIM_ + mt * 16) * N_ + nt64 * 64;
#pragma unroll
    for (int ns = 0; ns < 4; ++ns)
#pragma unroll
        for (int i = 0; i < 4; ++i)
            Cg[(size_t)(4 * g + i) * N_ + ns * 16 + c] = O4[ns][i];
}

extern "C" void kernel_launch(void* const* d_in, const int* in_sizes, int n_in,
                              void* d_out, int out_size, void* d_ws, size_t ws_size,
                              hipStream_t stream) {
    const float* fmap  = (const float*)d_in[0];
    const float* w_qkv = (const float*)d_in[1];
    const float* w_out = (const float*)d_in[2];
    float* out = (float*)d_out;

    char* ws = (char*)d_ws;
    // Overlay plan: xTg and wqF are dead after mm_qkv; attn's oh overlays them.
    half_t* perm = (half_t*)ws;                       // 25,165,824 B
    float*  sq   = (float*) (ws + 25165824);          //    524,288 B
    float*  lbuf = (float*) (ws + 25690112);          // 4 x 262,144 B
    half_t* woF  = (half_t*)(ws + 26738688);          //    262,144 B (read by mm_out)
    half_t* oh   = (half_t*)(ws + 27000832);          // 4 x 8,388,608 B (after mm_qkv)
    half_t* xTg  = (half_t*)(ws + 27000832);          //  4,194,304 B (aliases oh)
    half_t* wqF  = (half_t*)(ws + 31195136);          //    786,432 B (aliases oh)

    prep_all <<<624, 256, 0, stream>>>(fmap, w_qkv, w_out, wqF, woF, xTg);
    mm_qkv_mf<<<dim3(64, 24, 2), 256, 0, stream>>>(wqF, xTg, perm, sq);
    attn_mfma<<<dim3(64, 8, 2), 512, 0, stream>>>(perm, sq, oh, lbuf);
    mm_out_mf<<<dim3(64, 4, 2), 256, 0, stream>>>(woF, oh, lbuf, out);
}